// Round 3
// baseline (180.307 us; speedup 1.0000x reference)
//
#include <hip/hip_runtime.h>

// C[b,i,j,k,l,v] = sum_{mnop} A[b,m,i,v] A[b,n,j,v] A[b,o,k,v] A[b,p,l,v] C0[m,n,o,p]
// 4 voxels per thread (float4 I/O): wave stores are 1KB contiguous per inst,
// which keeps the HBM controller on large chunks (fill kernel proves dwordx4
// streams hit 6.7 TB/s at ~10% occupancy). Staged contraction, i outermost:
// peak live f4 regs = A(9) + t1(27) + t2(9) + t3(3) = 48 f4 = 192 VGPR.

#define GRID 64
#define NVOX (GRID * GRID * GRID)   // 262144 = 2^18
#define NV4  (NVOX / 4)             // 65536  = 2^16
#define NB 2

__device__ __forceinline__ float4 f4mulS(float4 v, float s) {
    float4 r; r.x = v.x * s; r.y = v.y * s; r.z = v.z * s; r.w = v.w * s; return r;
}
__device__ __forceinline__ float4 f4fmaS(float4 v, float s, float4 acc) {
    acc.x = fmaf(v.x, s, acc.x); acc.y = fmaf(v.y, s, acc.y);
    acc.z = fmaf(v.z, s, acc.z); acc.w = fmaf(v.w, s, acc.w); return acc;
}
__device__ __forceinline__ float4 f4mulV(float4 a, float4 b) {
    float4 r; r.x = a.x * b.x; r.y = a.y * b.y; r.z = a.z * b.z; r.w = a.w * b.w; return r;
}
__device__ __forceinline__ float4 f4fmaV(float4 a, float4 b, float4 acc) {
    acc.x = fmaf(a.x, b.x, acc.x); acc.y = fmaf(a.y, b.y, acc.y);
    acc.z = fmaf(a.z, b.z, acc.z); acc.w = fmaf(a.w, b.w, acc.w); return acc;
}

__global__ __launch_bounds__(256, 2) void alphaC0_kernel(
    const float4* __restrict__ a,   // (B,3,3,NVOX) viewed as (B,3,3,NV4) float4
    const float*  __restrict__ c0,  // (3,3,3,3)
    float4* __restrict__ out)       // (B,81,NV4) float4
{
    const int t = blockIdx.x * blockDim.x + threadIdx.x;  // [0, NB*NV4)
    const int b = t >> 16;
    const int vg = t & (NV4 - 1);

    // A[m][i] holds 4 voxels' alpha entries
    const float4* __restrict__ ab = a + (size_t)b * 9 * NV4 + vg;
    float4 A[3][3];
#pragma unroll
    for (int m = 0; m < 3; ++m)
#pragma unroll
        for (int i = 0; i < 3; ++i)
            A[m][i] = ab[(m * 3 + i) * NV4];

    float4* __restrict__ ob = out + (size_t)b * 81 * NV4 + vg;

#pragma unroll
    for (int i = 0; i < 3; ++i) {
        // Stage 1: t1[n][o][p] = sum_m A[m][i] * C0[m][n][o][p]  (c0 scalar/uniform)
        float4 t1[3][3][3];
#pragma unroll
        for (int n = 0; n < 3; ++n)
#pragma unroll
            for (int o = 0; o < 3; ++o)
#pragma unroll
                for (int p = 0; p < 3; ++p) {
                    float4 s = f4mulS(A[0][i], c0[((0 * 3 + n) * 3 + o) * 3 + p]);
                    s = f4fmaS(A[1][i], c0[((1 * 3 + n) * 3 + o) * 3 + p], s);
                    s = f4fmaS(A[2][i], c0[((2 * 3 + n) * 3 + o) * 3 + p], s);
                    t1[n][o][p] = s;
                }

#pragma unroll
        for (int j = 0; j < 3; ++j) {
            // Stage 2: t2[o][p] = sum_n A[n][j] * t1[n][o][p]  (per-lane vec*vec)
            float4 t2[3][3];
#pragma unroll
            for (int o = 0; o < 3; ++o)
#pragma unroll
                for (int p = 0; p < 3; ++p) {
                    float4 s = f4mulV(A[0][j], t1[0][o][p]);
                    s = f4fmaV(A[1][j], t1[1][o][p], s);
                    s = f4fmaV(A[2][j], t1[2][o][p], s);
                    t2[o][p] = s;
                }

#pragma unroll
            for (int k = 0; k < 3; ++k) {
                // Stage 3: t3[p] = sum_o A[o][k] * t2[o][p]
                float4 t3[3];
#pragma unroll
                for (int p = 0; p < 3; ++p) {
                    float4 s = f4mulV(A[0][k], t2[0][p]);
                    s = f4fmaV(A[1][k], t2[1][p], s);
                    s = f4fmaV(A[2][k], t2[2][p], s);
                    t3[p] = s;
                }

#pragma unroll
                for (int l = 0; l < 3; ++l) {
                    // Stage 4: C = sum_p A[p][l] * t3[p]
                    float4 s = f4mulV(A[0][l], t3[0]);
                    s = f4fmaV(A[1][l], t3[1], s);
                    s = f4fmaV(A[2][l], t3[2], s);
                    ob[(((i * 3 + j) * 3 + k) * 3 + l) * NV4] = s;
                }
            }
        }
    }
}

extern "C" void kernel_launch(void* const* d_in, const int* in_sizes, int n_in,
                              void* d_out, int out_size, void* d_ws, size_t ws_size,
                              hipStream_t stream) {
    const float4* a  = (const float4*)d_in[0];  // (2,3,3,64,64,64) fp32
    const float*  c0 = (const float*)d_in[1];   // (3,3,3,3) fp32
    float4* out = (float4*)d_out;               // (2,81,64^3) fp32

    const int total = NB * NV4;                 // 131072 threads
    const int block = 256;
    const int grid = total / block;             // 512
    alphaC0_kernel<<<grid, block, 0, stream>>>(a, c0, out);
}